// Round 16
// baseline (126.796 us; speedup 1.0000x reference)
//
#include <hip/hip_runtime.h>
#include <hip/hip_bf16.h>
#include <stdint.h>

#define B_ROWS 6144
#define N_ROWS 12288
#define DIM 256
#define NCLASS 512
#define MREP 3
#define ITILE 192                  // 4 waves * 48 rows; also j-tile height
#define NT (N_ROWS / ITILE)        // 64 tile grid -> 64*65/2 = 2080 blocks
#define NBLK (NT * (NT + 1) / 2)   // 2080
#define NITER 6                    // 192 j-rows / 32 per iteration
#define SCALE 14.426950408889634f  // log2(e)/0.1
#define PRESCALE 3.798282432f      // sqrt(SCALE); folded into embeddings
#define NCBLK NCLASS               // 512 classum blocks
#define WLCAP 128
#define PREPBLK (N_ROWS / 16)      // 768 prep blocks @1024 thr
#define FINBLK (N_ROWS / 256)      // 48
#define OFFS(t) ((t) * NT - (((t) * ((t)-1)) >> 1))

typedef float f32x4 __attribute__((ext_vector_type(4)));
typedef __bf16 bf16x8 __attribute__((ext_vector_type(8)));
typedef __bf16 bf16x4 __attribute__((ext_vector_type(4)));

// ---- workspace layout (bytes) ----
// ebf: swizzled bf16 of sqrt(SCALE)*normalized rows. Panel p = row>>4 (8 KB):
//   elem(row,d) = p*4096 + (d>>5)*512 + ((d>>3)&3)*128 + (row&15)*8 + (d&7)
// ps: PER-BLOCK SLABS, 384 floats each, block-exclusive:
//   slab[bid][0..191] = s_i (rows of tile ti vs tile tj),
//   slab[bid][192..383] = s_j (rows of tile tj vs tile ti; off-diag only).
#define WS_EBF  ((size_t)0)
#define WS_PS   ((size_t)(N_ROWS * DIM * 2))              // 6,291,456
#define WS_PSUM (WS_PS + (size_t)NBLK * 384 * 4)          // + 3,194,880
#define WS_PART (WS_PSUM + (size_t)NCLASS * 4)            // + 2,048
#define WS_CNT  (WS_PART + (size_t)FINBLK * 4)            // + 192

__device__ inline void gload_lds16(const void* g, void* l) {
  __builtin_amdgcn_global_load_lds(
      (const __attribute__((address_space(1))) unsigned int*)g,
      (__attribute__((address_space(3))) unsigned int*)l, 16, 0, 0);
}

__device__ inline float block_sum_256(float v, float* sbuf) {
#pragma unroll
  for (int off = 32; off; off >>= 1) v += __shfl_down(v, off);
  const int lane = threadIdx.x & 63;
  const int w = threadIdx.x >> 6;
  __syncthreads();
  if (lane == 0) sbuf[w] = v;
  __syncthreads();
  return sbuf[0] + sbuf[1] + sbuf[2] + sbuf[3];
}

__device__ inline float block_sum_1024(float v, float* sbuf16) {
#pragma unroll
  for (int off = 32; off; off >>= 1) v += __shfl_down(v, off);
  const int lane = threadIdx.x & 63;
  const int w = threadIdx.x >> 6;
  __syncthreads();
  if (lane == 0) sbuf16[w] = v;
  __syncthreads();
  float t = 0.f;
#pragma unroll
  for (int i = 0; i < 16; ++i) t += sbuf16[i];
  return t;
}

// Kernel A (merged, 1024 threads): unchanged (proven R11).
__global__ __launch_bounds__(1024) void prep_classum_kernel(
    const float* __restrict__ o1, const float* __restrict__ o2,
    const long long* __restrict__ lab64, __bf16* __restrict__ ebf,
    float* __restrict__ psum) {
  __shared__ unsigned short wl[WLCAP];
  __shared__ int woff[16];
  __shared__ float spart[16][DIM];
  __shared__ float sbuf16[16];
  const int tid = threadIdx.x;
  const int lane = tid & 63;
  const int wv = tid >> 6;

  if (blockIdx.x >= NCBLK) {
    const int row = (blockIdx.x - NCBLK) * 16 + wv;
    const float* src = (row < B_ROWS) ? (o1 + (size_t)row * DIM)
                                      : (o2 + (size_t)(row - B_ROWS) * DIM);
    const float4 v = ((const float4*)src)[lane];
    float ss = v.x * v.x + v.y * v.y + v.z * v.z + v.w * v.w;
#pragma unroll
    for (int off = 1; off < 64; off <<= 1) ss += __shfl_xor(ss, off);
    const float rn = PRESCALE / fmaxf(sqrtf(ss), 1e-12f);
    bf16x4 h;
    h[0] = (__bf16)(v.x * rn); h[1] = (__bf16)(v.y * rn);
    h[2] = (__bf16)(v.z * rn); h[3] = (__bf16)(v.w * rn);
    const int p = row >> 4, r = row & 15;
    *(bf16x4*)(ebf + (size_t)p * 4096 + (lane >> 3) * 512 + ((lane >> 1) & 3) * 128
               + r * 8 + (lane & 1) * 4) = h;
    return;
  }

  const int c = blockIdx.x;
  unsigned long long bits = 0ull;
  int mycnt = 0;
#pragma unroll
  for (int it = 0; it < N_ROWS / 1024; ++it) {
    const int k = tid + it * 1024;
    const int lr = (k < B_ROWS) ? k : k - B_ROWS;
    if ((int)lab64[lr] == c) { bits |= (1ull << it); ++mycnt; }
  }
  int pre = mycnt;
#pragma unroll
  for (int off = 1; off < 64; off <<= 1) {
    const int o = __shfl_up(pre, off);
    if (lane >= off) pre += o;
  }
  if (lane == 63) woff[wv] = pre;
  __syncthreads();
  int wbase = 0, n = 0;
#pragma unroll
  for (int i = 0; i < 16; ++i) {
    const int wi = woff[i];
    wbase += (i < wv) ? wi : 0;
    n += wi;
  }
  if (n > WLCAP) n = WLCAP;
  int o = wbase + pre - mycnt;
#pragma unroll
  for (int it = 0; it < N_ROWS / 1024; ++it) {
    if ((bits >> it) & 1ull) {
      if (o < WLCAP) wl[o] = (unsigned short)(tid + it * 1024);
      ++o;
    }
  }
  __syncthreads();

  float4 a = {0.f, 0.f, 0.f, 0.f};
  for (int u = wv; u < n; u += 16) {
    const int row = wl[u];
    const float* src = (row < B_ROWS) ? (o1 + (size_t)row * DIM)
                                      : (o2 + (size_t)(row - B_ROWS) * DIM);
    const float4 v = ((const float4*)src)[lane];
    float ss = v.x * v.x + v.y * v.y + v.z * v.z + v.w * v.w;
#pragma unroll
    for (int off = 1; off < 64; off <<= 1) ss += __shfl_xor(ss, off);
    const float r = 1.0f / fmaxf(sqrtf(ss), 1e-12f);
    a.x += v.x * r; a.y += v.y * r; a.z += v.z * r; a.w += v.w * r;
  }
  *(float4*)&spart[wv][lane * 4] = a;
  __syncthreads();

  float s = 0.f;
  if (tid < DIM) {
#pragma unroll
    for (int i = 0; i < 16; ++i) s += spart[i][tid];
  }
  const float r2 = block_sum_1024(s * s, sbuf16);
  if (tid == 0) psum[c] = (n > 0) ? r2 / (float)n : 0.f;
}

// Kernel B: SYMMETRIC streaming exp-sums, upper-tri tile pairs (ti <= tj).
// Body byte-identical to R12's passing kernel; block-exclusive slab writes.
__global__ __launch_bounds__(256, 3) void lse_kernel(const __bf16* __restrict__ ebf,
                                                     float* __restrict__ ps) {
  __shared__ __align__(16) char smem[3 * 16384];
  __shared__ float sjacc[4][ITILE];   // per-wave col partials, 3 KB
  const int bid = blockIdx.x;
  int ti = (int)((2.0f * NT + 1.0f
                  - sqrtf((2.0f * NT + 1.0f) * (2.0f * NT + 1.0f) - 8.0f * (float)bid))
                 * 0.5f);
  if (ti < 0) ti = 0;
  if (ti > NT - 1) ti = NT - 1;
  while (ti < NT - 1 && OFFS(ti + 1) <= bid) ++ti;
  while (ti > 0 && OFFS(ti) > bid) --ti;
  const int tj = ti + (bid - OFFS(ti));
  const int i0 = ti * ITILE;
  const int j0 = tj * ITILE;
  const int tid = threadIdx.x;
  const int lane = tid & 63;
  const int w = tid >> 6;
  const char* const base = (const char*)ebf;
  float* const myslab = ps + (size_t)bid * 384;

  for (int idx = tid; idx < 4 * ITILE; idx += 256) ((float*)sjacc)[idx] = 0.f;

  bf16x8 a[MREP][8];
  {
    const char* ap = base + (size_t)((i0 >> 4) + w * MREP) * 8192 + lane * 16;
#pragma unroll
    for (int m = 0; m < MREP; ++m)
#pragma unroll
      for (int kc = 0; kc < 8; ++kc)
        a[m][kc] = *(const bf16x8*)(ap + m * 8192 + kc * 1024);
  }

  float s[MREP][4];
#pragma unroll
  for (int m = 0; m < MREP; ++m)
#pragma unroll
    for (int r = 0; r < 4; ++r) s[m][r] = 0.0f;

  const char* gsrc0 = base + (size_t)(j0 >> 4) * 8192 + w * 1024 + lane * 16;

#pragma unroll
  for (int q = 0; q < 4; ++q)
    gload_lds16(gsrc0 + q * 4096, smem + w * 1024 + q * 4096);
#pragma unroll
  for (int q = 0; q < 4; ++q)
    gload_lds16(gsrc0 + 16384 + q * 4096, smem + 16384 + w * 1024 + q * 4096);
  __syncthreads();

  int bsel = 0;
  for (int t = 0; t < NITER; ++t) {
    if (t + 2 < NITER) {
      const char* gs = gsrc0 + (size_t)(t + 2) * 16384;
      char* ldst = smem + ((bsel + 2) % 3) * 16384 + w * 1024;
#pragma unroll
      for (int q = 0; q < 4; ++q) gload_lds16(gs + q * 4096, ldst + q * 4096);
    }

    const char* lb = smem + bsel * 16384 + lane * 16;
    f32x4 acc[MREP][2];
#pragma unroll
    for (int m = 0; m < MREP; ++m) {
      acc[m][0] = (f32x4){0.0f, 0.0f, 0.0f, 0.0f};
      acc[m][1] = (f32x4){0.0f, 0.0f, 0.0f, 0.0f};
    }
    __builtin_amdgcn_s_setprio(1);
#pragma unroll
    for (int kc = 0; kc < 8; ++kc) {
      const bf16x8 b0 = *(const bf16x8*)(lb + kc * 1024);
      const bf16x8 b1 = *(const bf16x8*)(lb + kc * 1024 + 8192);
#pragma unroll
      for (int m = 0; m < MREP; ++m) {
        acc[m][0] = __builtin_amdgcn_mfma_f32_16x16x32_bf16(a[m][kc], b0, acc[m][0], 0, 0, 0);
        acc[m][1] = __builtin_amdgcn_mfma_f32_16x16x32_bf16(a[m][kc], b1, acc[m][1], 0, 0, 0);
      }
    }
    __builtin_amdgcn_s_setprio(0);
    float p0 = 0.f, p1 = 0.f;
#pragma unroll
    for (int m = 0; m < MREP; ++m)
#pragma unroll
      for (int r = 0; r < 4; ++r) {
        const float e0 = __builtin_amdgcn_exp2f(acc[m][0][r]);
        const float e1 = __builtin_amdgcn_exp2f(acc[m][1][r]);
        s[m][r] += e0 + e1;
        p0 += e0;
        p1 += e1;
      }
    p0 += __shfl_xor(p0, 16); p0 += __shfl_xor(p0, 32);
    p1 += __shfl_xor(p1, 16); p1 += __shfl_xor(p1, 32);
    if (lane < 16) {
      sjacc[w][t * 32 + lane] += p0;
      sjacc[w][t * 32 + 16 + lane] += p1;
    }

    __builtin_amdgcn_sched_barrier(0);
    asm volatile("s_waitcnt lgkmcnt(0)" ::: "memory");
    if (t + 2 < NITER) {
      asm volatile("s_waitcnt vmcnt(4)" ::: "memory");
    } else {
      asm volatile("s_waitcnt vmcnt(0)" ::: "memory");
    }
    __builtin_amdgcn_sched_barrier(0);
    __builtin_amdgcn_s_barrier();
    __builtin_amdgcn_sched_barrier(0);

    bsel = (bsel + 1) % 3;
  }

  // s_i: merge across the 16 lanes sharing the same output rows
#pragma unroll
  for (int off = 1; off < 16; off <<= 1)
#pragma unroll
    for (int m = 0; m < MREP; ++m)
#pragma unroll
      for (int r = 0; r < 4; ++r)
        s[m][r] += __shfl_xor(s[m][r], off);

  if ((lane & 15) == 0) {
    const int g = lane >> 4;
#pragma unroll
    for (int m = 0; m < MREP; ++m)
#pragma unroll
      for (int r = 0; r < 4; ++r)
        myslab[w * 48 + m * 16 + g * 4 + r] = s[m][r];
  }

  // s_j: reduce wave partials, write (off-diagonal blocks only)
  __syncthreads();
  if (ti != tj) {
    for (int col = tid; col < ITILE; col += 256) {
      const float v = sjacc[0][col] + sjacc[1][col] + sjacc[2][col] + sjacc[3][col];
      myslab[192 + col] = v;
    }
  }
}

// Kernel C (fused finish+mean): 48 blocks; gather per-row contributions from
// block slabs. cnt is zeroed by a captured memset each launch, so the 48th
// atomicAdd arrival (old == FINBLK-1) is genuinely the last block.
__global__ __launch_bounds__(256) void finishmean_kernel(
    const float* __restrict__ ps, const float* __restrict__ psum,
    float* __restrict__ partial, unsigned int* __restrict__ cnt,
    float* __restrict__ out) {
  __shared__ float sbuf[4];
  __shared__ int is_last;
  const int tid = threadIdx.x;
  const int row = blockIdx.x * 256 + tid;
  const int tr = row / ITILE;
  const int k = row - tr * ITILE;
  const int offs_tr = OFFS(tr);
  float sm = 0.f;
#pragma unroll
  for (int c = 0; c < NT; ++c) {
    const int idx = (c >= tr) ? ((offs_tr + c - tr) * 384 + k)
                              : ((OFFS(c) + tr - c) * 384 + 192 + k);
    sm += ps[idx];
  }
  const float p = block_sum_256(logf(sm), sbuf);
  if (tid == 0) {
    partial[blockIdx.x] = p;
    __threadfence();
    const unsigned int old = atomicAdd(cnt, 1u);
    is_last = (old == (unsigned)(FINBLK - 1)) ? 1 : 0;
  }
  __syncthreads();
  if (!is_last) return;
  __threadfence();
  float v = (tid < FINBLK) ? atomicAdd(&partial[tid], 0.0f) : 0.0f;
  const float vs = block_sum_256(v, sbuf);
  const float qs = block_sum_256(psum[tid] + psum[tid + 256], sbuf);
  if (tid == 0)
    out[0] = vs * (1.0f / (float)N_ROWS) - qs * (10.0f / (float)N_ROWS);
}

extern "C" void kernel_launch(void* const* d_in, const int* in_sizes, int n_in,
                              void* d_out, int out_size, void* d_ws, size_t ws_size,
                              hipStream_t stream) {
  const float* o1 = (const float*)d_in[0];
  const float* o2 = (const float*)d_in[1];
  const long long* labels = (const long long*)d_in[2];
  char* ws = (char*)d_ws;
  __bf16* ebf = (__bf16*)(ws + WS_EBF);
  float* ps = (float*)(ws + WS_PS);
  float* psum = (float*)(ws + WS_PSUM);
  float* partial = (float*)(ws + WS_PART);
  unsigned int* cnt = (unsigned int*)(ws + WS_CNT);

  // R16 fix: cnt must start at 0 for last-block detection; captured into the
  // graph so every replay re-zeroes it. (R13-R15 "layout bugs" were this.)
  hipMemsetAsync(cnt, 0, sizeof(unsigned int), stream);
  prep_classum_kernel<<<NCBLK + PREPBLK, 1024, 0, stream>>>(o1, o2, labels, ebf, psum);
  lse_kernel<<<NBLK, 256, 0, stream>>>(ebf, ps);
  finishmean_kernel<<<FINBLK, 256, 0, stream>>>(ps, psum, partial, cnt, (float*)d_out);
}

// Round 17
// 122.104 us; speedup vs baseline: 1.0384x; 1.0384x over previous
//
#include <hip/hip_runtime.h>
#include <hip/hip_bf16.h>
#include <stdint.h>

#define B_ROWS 6144
#define N_ROWS 12288
#define DIM 256
#define NCLASS 512
#define MREP 3
#define ITILE 192                  // 4 waves * 48 rows; also j-tile height
#define NT (N_ROWS / ITILE)        // 64 tile grid -> 64*65/2 = 2080 blocks
#define NBLK (NT * (NT + 1) / 2)   // 2080 = 8 XCDs * 260
#define NITER 6                    // 192 j-rows / 32 per iteration
#define SCALE 14.426950408889634f  // log2(e)/0.1
#define PRESCALE 3.798282432f      // sqrt(SCALE); folded into embeddings
#define NCBLK NCLASS               // 512 classum blocks
#define WLCAP 128
#define PREPBLK (N_ROWS / 16)      // 768 prep blocks @1024 thr
#define FINBLK (N_ROWS / 256)      // 48
#define OFFS(t) ((t) * NT - (((t) * ((t)-1)) >> 1))

typedef float f32x4 __attribute__((ext_vector_type(4)));
typedef __bf16 bf16x8 __attribute__((ext_vector_type(8)));
typedef __bf16 bf16x4 __attribute__((ext_vector_type(4)));

// ---- workspace layout (bytes) ----
// ebf: swizzled bf16 of sqrt(SCALE)*normalized rows. Panel p = row>>4 (8 KB):
//   elem(row,d) = p*4096 + (d>>5)*512 + ((d>>3)&3)*128 + (row&15)*8 + (d&7)
// ps: PER-PAIR SLABS (canonical index OFFS(ti)+tj-ti), 384 floats each:
//   slab[0..191] = s_i, slab[192..383] = s_j (off-diag only).
#define WS_EBF  ((size_t)0)
#define WS_PS   ((size_t)(N_ROWS * DIM * 2))              // 6,291,456
#define WS_PSUM (WS_PS + (size_t)NBLK * 384 * 4)          // + 3,194,880
#define WS_PART (WS_PSUM + (size_t)NCLASS * 4)            // + 2,048
#define WS_CNT  (WS_PART + (size_t)FINBLK * 4)            // + 192

__device__ inline void gload_lds16(const void* g, void* l) {
  __builtin_amdgcn_global_load_lds(
      (const __attribute__((address_space(1))) unsigned int*)g,
      (__attribute__((address_space(3))) unsigned int*)l, 16, 0, 0);
}

__device__ inline float block_sum_256(float v, float* sbuf) {
#pragma unroll
  for (int off = 32; off; off >>= 1) v += __shfl_down(v, off);
  const int lane = threadIdx.x & 63;
  const int w = threadIdx.x >> 6;
  __syncthreads();
  if (lane == 0) sbuf[w] = v;
  __syncthreads();
  return sbuf[0] + sbuf[1] + sbuf[2] + sbuf[3];
}

__device__ inline float block_sum_1024(float v, float* sbuf16) {
#pragma unroll
  for (int off = 32; off; off >>= 1) v += __shfl_down(v, off);
  const int lane = threadIdx.x & 63;
  const int w = threadIdx.x >> 6;
  __syncthreads();
  if (lane == 0) sbuf16[w] = v;
  __syncthreads();
  float t = 0.f;
#pragma unroll
  for (int i = 0; i < 16; ++i) t += sbuf16[i];
  return t;
}

// Kernel A (merged, 1024 threads): unchanged (proven R11).
__global__ __launch_bounds__(1024) void prep_classum_kernel(
    const float* __restrict__ o1, const float* __restrict__ o2,
    const long long* __restrict__ lab64, __bf16* __restrict__ ebf,
    float* __restrict__ psum) {
  __shared__ unsigned short wl[WLCAP];
  __shared__ int woff[16];
  __shared__ float spart[16][DIM];
  __shared__ float sbuf16[16];
  const int tid = threadIdx.x;
  const int lane = tid & 63;
  const int wv = tid >> 6;

  if (blockIdx.x >= NCBLK) {
    const int row = (blockIdx.x - NCBLK) * 16 + wv;
    const float* src = (row < B_ROWS) ? (o1 + (size_t)row * DIM)
                                      : (o2 + (size_t)(row - B_ROWS) * DIM);
    const float4 v = ((const float4*)src)[lane];
    float ss = v.x * v.x + v.y * v.y + v.z * v.z + v.w * v.w;
#pragma unroll
    for (int off = 1; off < 64; off <<= 1) ss += __shfl_xor(ss, off);
    const float rn = PRESCALE / fmaxf(sqrtf(ss), 1e-12f);
    bf16x4 h;
    h[0] = (__bf16)(v.x * rn); h[1] = (__bf16)(v.y * rn);
    h[2] = (__bf16)(v.z * rn); h[3] = (__bf16)(v.w * rn);
    const int p = row >> 4, r = row & 15;
    *(bf16x4*)(ebf + (size_t)p * 4096 + (lane >> 3) * 512 + ((lane >> 1) & 3) * 128
               + r * 8 + (lane & 1) * 4) = h;
    return;
  }

  const int c = blockIdx.x;
  unsigned long long bits = 0ull;
  int mycnt = 0;
#pragma unroll
  for (int it = 0; it < N_ROWS / 1024; ++it) {
    const int k = tid + it * 1024;
    const int lr = (k < B_ROWS) ? k : k - B_ROWS;
    if ((int)lab64[lr] == c) { bits |= (1ull << it); ++mycnt; }
  }
  int pre = mycnt;
#pragma unroll
  for (int off = 1; off < 64; off <<= 1) {
    const int o = __shfl_up(pre, off);
    if (lane >= off) pre += o;
  }
  if (lane == 63) woff[wv] = pre;
  __syncthreads();
  int wbase = 0, n = 0;
#pragma unroll
  for (int i = 0; i < 16; ++i) {
    const int wi = woff[i];
    wbase += (i < wv) ? wi : 0;
    n += wi;
  }
  if (n > WLCAP) n = WLCAP;
  int o = wbase + pre - mycnt;
#pragma unroll
  for (int it = 0; it < N_ROWS / 1024; ++it) {
    if ((bits >> it) & 1ull) {
      if (o < WLCAP) wl[o] = (unsigned short)(tid + it * 1024);
      ++o;
    }
  }
  __syncthreads();

  float4 a = {0.f, 0.f, 0.f, 0.f};
  for (int u = wv; u < n; u += 16) {
    const int row = wl[u];
    const float* src = (row < B_ROWS) ? (o1 + (size_t)row * DIM)
                                      : (o2 + (size_t)(row - B_ROWS) * DIM);
    const float4 v = ((const float4*)src)[lane];
    float ss = v.x * v.x + v.y * v.y + v.z * v.z + v.w * v.w;
#pragma unroll
    for (int off = 1; off < 64; off <<= 1) ss += __shfl_xor(ss, off);
    const float r = 1.0f / fmaxf(sqrtf(ss), 1e-12f);
    a.x += v.x * r; a.y += v.y * r; a.z += v.z * r; a.w += v.w * r;
  }
  *(float4*)&spart[wv][lane * 4] = a;
  __syncthreads();

  float s = 0.f;
  if (tid < DIM) {
#pragma unroll
    for (int i = 0; i < 16; ++i) s += spart[i][tid];
  }
  const float r2 = block_sum_1024(s * s, sbuf16);
  if (tid == 0) psum[c] = (n > 0) ? r2 / (float)n : 0.f;
}

// Kernel B: SYMMETRIC streaming exp-sums, upper-tri tile pairs (ti <= tj).
// R17: supertile-major pair order, XCD-partitioned (bid&7 = XCD, contiguous
// 260-pair range per XCD) -> per-XCD L2 working set 1.5-3 MB (< 4 MB).
// Compute body byte-identical to R16 (passing). Slab = canonical pair index.
__global__ __launch_bounds__(256, 3) void lse_kernel(const __bf16* __restrict__ ebf,
                                                     float* __restrict__ ps) {
  __shared__ __align__(16) char smem[3 * 16384];
  __shared__ float sjacc[4][ITILE];   // per-wave col partials, 3 KB
  const int bid = blockIdx.x;

  // supertile-major pair index, XCD-partitioned
  const int p = (bid & 7) * (NBLK / 8) + (bid >> 3);
  int si = 0, sj = 0, q = p;
#pragma unroll 1
  for (si = 0; si < 8; ++si) {
    bool found = false;
#pragma unroll 1
    for (sj = si; sj < 8; ++sj) {
      const int sz = (si == sj) ? 36 : 64;
      if (q < sz) { found = true; break; }
      q -= sz;
    }
    if (found) break;
  }
  int ui, uj;
  if (si == sj) {   // diagonal supertile: q -> upper-tri 8x8
    ui = 0;
    int rem = q;
#pragma unroll 1
    while (rem >= 8 - ui) { rem -= (8 - ui); ++ui; }
    uj = ui + rem;
  } else {
    ui = q >> 3;
    uj = q & 7;
  }
  const int ti = si * 8 + ui;
  const int tj = sj * 8 + uj;
  const int i0 = ti * ITILE;
  const int j0 = tj * ITILE;
  const int tid = threadIdx.x;
  const int lane = tid & 63;
  const int w = tid >> 6;
  const char* const base = (const char*)ebf;
  float* const myslab = ps + (size_t)(OFFS(ti) + (tj - ti)) * 384;

  for (int idx = tid; idx < 4 * ITILE; idx += 256) ((float*)sjacc)[idx] = 0.f;

  bf16x8 a[MREP][8];
  {
    const char* ap = base + (size_t)((i0 >> 4) + w * MREP) * 8192 + lane * 16;
#pragma unroll
    for (int m = 0; m < MREP; ++m)
#pragma unroll
      for (int kc = 0; kc < 8; ++kc)
        a[m][kc] = *(const bf16x8*)(ap + m * 8192 + kc * 1024);
  }

  float s[MREP][4];
#pragma unroll
  for (int m = 0; m < MREP; ++m)
#pragma unroll
    for (int r = 0; r < 4; ++r) s[m][r] = 0.0f;

  const char* gsrc0 = base + (size_t)(j0 >> 4) * 8192 + w * 1024 + lane * 16;

#pragma unroll
  for (int q2 = 0; q2 < 4; ++q2)
    gload_lds16(gsrc0 + q2 * 4096, smem + w * 1024 + q2 * 4096);
#pragma unroll
  for (int q2 = 0; q2 < 4; ++q2)
    gload_lds16(gsrc0 + 16384 + q2 * 4096, smem + 16384 + w * 1024 + q2 * 4096);
  __syncthreads();

  int bsel = 0;
  for (int t = 0; t < NITER; ++t) {
    if (t + 2 < NITER) {
      const char* gs = gsrc0 + (size_t)(t + 2) * 16384;
      char* ldst = smem + ((bsel + 2) % 3) * 16384 + w * 1024;
#pragma unroll
      for (int q2 = 0; q2 < 4; ++q2) gload_lds16(gs + q2 * 4096, ldst + q2 * 4096);
    }

    const char* lb = smem + bsel * 16384 + lane * 16;
    f32x4 acc[MREP][2];
#pragma unroll
    for (int m = 0; m < MREP; ++m) {
      acc[m][0] = (f32x4){0.0f, 0.0f, 0.0f, 0.0f};
      acc[m][1] = (f32x4){0.0f, 0.0f, 0.0f, 0.0f};
    }
    __builtin_amdgcn_s_setprio(1);
#pragma unroll
    for (int kc = 0; kc < 8; ++kc) {
      const bf16x8 b0 = *(const bf16x8*)(lb + kc * 1024);
      const bf16x8 b1 = *(const bf16x8*)(lb + kc * 1024 + 8192);
#pragma unroll
      for (int m = 0; m < MREP; ++m) {
        acc[m][0] = __builtin_amdgcn_mfma_f32_16x16x32_bf16(a[m][kc], b0, acc[m][0], 0, 0, 0);
        acc[m][1] = __builtin_amdgcn_mfma_f32_16x16x32_bf16(a[m][kc], b1, acc[m][1], 0, 0, 0);
      }
    }
    __builtin_amdgcn_s_setprio(0);
    float p0 = 0.f, p1 = 0.f;
#pragma unroll
    for (int m = 0; m < MREP; ++m)
#pragma unroll
      for (int r = 0; r < 4; ++r) {
        const float e0 = __builtin_amdgcn_exp2f(acc[m][0][r]);
        const float e1 = __builtin_amdgcn_exp2f(acc[m][1][r]);
        s[m][r] += e0 + e1;
        p0 += e0;
        p1 += e1;
      }
    p0 += __shfl_xor(p0, 16); p0 += __shfl_xor(p0, 32);
    p1 += __shfl_xor(p1, 16); p1 += __shfl_xor(p1, 32);
    if (lane < 16) {
      sjacc[w][t * 32 + lane] += p0;
      sjacc[w][t * 32 + 16 + lane] += p1;
    }

    __builtin_amdgcn_sched_barrier(0);
    asm volatile("s_waitcnt lgkmcnt(0)" ::: "memory");
    if (t + 2 < NITER) {
      asm volatile("s_waitcnt vmcnt(4)" ::: "memory");
    } else {
      asm volatile("s_waitcnt vmcnt(0)" ::: "memory");
    }
    __builtin_amdgcn_sched_barrier(0);
    __builtin_amdgcn_s_barrier();
    __builtin_amdgcn_sched_barrier(0);

    bsel = (bsel + 1) % 3;
  }

  // s_i: merge across the 16 lanes sharing the same output rows
#pragma unroll
  for (int off = 1; off < 16; off <<= 1)
#pragma unroll
    for (int m = 0; m < MREP; ++m)
#pragma unroll
      for (int r = 0; r < 4; ++r)
        s[m][r] += __shfl_xor(s[m][r], off);

  if ((lane & 15) == 0) {
    const int g = lane >> 4;
#pragma unroll
    for (int m = 0; m < MREP; ++m)
#pragma unroll
      for (int r = 0; r < 4; ++r)
        myslab[w * 48 + m * 16 + g * 4 + r] = s[m][r];
  }

  // s_j: reduce wave partials, write (off-diagonal blocks only)
  __syncthreads();
  if (ti != tj) {
    for (int col = tid; col < ITILE; col += 256) {
      const float v = sjacc[0][col] + sjacc[1][col] + sjacc[2][col] + sjacc[3][col];
      myslab[192 + col] = v;
    }
  }
}

// Kernel C (fused finish+mean): 48 blocks; gather per-row contributions from
// canonical pair slabs. cnt zeroed by captured memset each launch.
__global__ __launch_bounds__(256) void finishmean_kernel(
    const float* __restrict__ ps, const float* __restrict__ psum,
    float* __restrict__ partial, unsigned int* __restrict__ cnt,
    float* __restrict__ out) {
  __shared__ float sbuf[4];
  __shared__ int is_last;
  const int tid = threadIdx.x;
  const int row = blockIdx.x * 256 + tid;
  const int tr = row / ITILE;
  const int k = row - tr * ITILE;
  const int offs_tr = OFFS(tr);
  float sm = 0.f;
#pragma unroll
  for (int c = 0; c < NT; ++c) {
    const int idx = (c >= tr) ? ((offs_tr + c - tr) * 384 + k)
                              : ((OFFS(c) + tr - c) * 384 + 192 + k);
    sm += ps[idx];
  }
  const float p = block_sum_256(logf(sm), sbuf);
  if (tid == 0) {
    partial[blockIdx.x] = p;
    __threadfence();
    const unsigned int old = atomicAdd(cnt, 1u);
    is_last = (old == (unsigned)(FINBLK - 1)) ? 1 : 0;
  }
  __syncthreads();
  if (!is_last) return;
  __threadfence();
  float v = (tid < FINBLK) ? atomicAdd(&partial[tid], 0.0f) : 0.0f;
  const float vs = block_sum_256(v, sbuf);
  const float qs = block_sum_256(psum[tid] + psum[tid + 256], sbuf);
  if (tid == 0)
    out[0] = vs * (1.0f / (float)N_ROWS) - qs * (10.0f / (float)N_ROWS);
}

extern "C" void kernel_launch(void* const* d_in, const int* in_sizes, int n_in,
                              void* d_out, int out_size, void* d_ws, size_t ws_size,
                              hipStream_t stream) {
  const float* o1 = (const float*)d_in[0];
  const float* o2 = (const float*)d_in[1];
  const long long* labels = (const long long*)d_in[2];
  char* ws = (char*)d_ws;
  __bf16* ebf = (__bf16*)(ws + WS_EBF);
  float* ps = (float*)(ws + WS_PS);
  float* psum = (float*)(ws + WS_PSUM);
  float* partial = (float*)(ws + WS_PART);
  unsigned int* cnt = (unsigned int*)(ws + WS_CNT);

  hipMemsetAsync(cnt, 0, sizeof(unsigned int), stream);
  prep_classum_kernel<<<NCBLK + PREPBLK, 1024, 0, stream>>>(o1, o2, labels, ebf, psum);
  lse_kernel<<<NBLK, 256, 0, stream>>>(ebf, ps);
  finishmean_kernel<<<FINBLK, 256, 0, stream>>>(ps, psum, partial, cnt, (float*)d_out);
}

// Round 18
// 91.195 us; speedup vs baseline: 1.3904x; 1.3389x over previous
//
#include <hip/hip_runtime.h>
#include <hip/hip_bf16.h>
#include <stdint.h>

#define B_ROWS 6144
#define N_ROWS 12288
#define DIM 256
#define NCLASS 512
#define NCHUNK 12
#define JCHUNK (N_ROWS / NCHUNK)   // 1024
#define NITER (JCHUNK / 32)        // 32
#define MREP 3
#define ITILE 192                  // 4 waves * 48 rows
#define NITILE (N_ROWS / ITILE)    // 64 -> grid 768 = 3 blocks/CU
#define SCALE 14.426950408889634f  // log2(e)/0.1
#define PRESCALE 3.798282432f      // sqrt(SCALE); folded into embeddings
#define NCBLK NCLASS               // 512 classum blocks
#define WLCAP 128
#define PREPBLK (N_ROWS / 16)      // 768 prep blocks @1024 thr
#define FINBLK (N_ROWS / 256)      // 48

typedef float f32x4 __attribute__((ext_vector_type(4)));
typedef __bf16 bf16x8 __attribute__((ext_vector_type(8)));
typedef __bf16 bf16x4 __attribute__((ext_vector_type(4)));

// ---- workspace layout (bytes) ----
// ebf: swizzled bf16 of sqrt(SCALE)*normalized rows. Panel p = row>>4 (8 KB):
//   elem(row,d) = p*4096 + (d>>5)*512 + ((d>>3)&3)*128 + (row&15)*8 + (d&7)
#define WS_EBF  ((size_t)0)
#define WS_PS   ((size_t)(N_ROWS * DIM * 2))              // 6,291,456
#define WS_PSUM (WS_PS + (size_t)N_ROWS * NCHUNK * 4)     // + 589,824
#define WS_PART (WS_PSUM + (size_t)NCLASS * 4)            // + 2,048
#define WS_CNT  (WS_PART + (size_t)FINBLK * 4)            // + 192

__device__ inline void gload_lds16(const void* g, void* l) {
  __builtin_amdgcn_global_load_lds(
      (const __attribute__((address_space(1))) unsigned int*)g,
      (__attribute__((address_space(3))) unsigned int*)l, 16, 0, 0);
}

__device__ inline float block_sum_256(float v, float* sbuf) {
#pragma unroll
  for (int off = 32; off; off >>= 1) v += __shfl_down(v, off);
  const int lane = threadIdx.x & 63;
  const int w = threadIdx.x >> 6;
  __syncthreads();
  if (lane == 0) sbuf[w] = v;
  __syncthreads();
  return sbuf[0] + sbuf[1] + sbuf[2] + sbuf[3];
}

__device__ inline float block_sum_1024(float v, float* sbuf16) {
#pragma unroll
  for (int off = 32; off; off >>= 1) v += __shfl_down(v, off);
  const int lane = threadIdx.x & 63;
  const int w = threadIdx.x >> 6;
  __syncthreads();
  if (lane == 0) sbuf16[w] = v;
  __syncthreads();
  float t = 0.f;
#pragma unroll
  for (int i = 0; i < 16; ++i) t += sbuf16[i];
  return t;
}

// Kernel A (merged, 1024 threads): blocks [0, NCBLK) = class-major positive
// term; blocks [NCBLK, ...) = prep. Proven R11.
__global__ __launch_bounds__(1024) void prep_classum_kernel(
    const float* __restrict__ o1, const float* __restrict__ o2,
    const long long* __restrict__ lab64, __bf16* __restrict__ ebf,
    float* __restrict__ psum) {
  __shared__ unsigned short wl[WLCAP];
  __shared__ int woff[16];
  __shared__ float spart[16][DIM];
  __shared__ float sbuf16[16];
  const int tid = threadIdx.x;
  const int lane = tid & 63;
  const int wv = tid >> 6;

  if (blockIdx.x >= NCBLK) {
    const int row = (blockIdx.x - NCBLK) * 16 + wv;
    const float* src = (row < B_ROWS) ? (o1 + (size_t)row * DIM)
                                      : (o2 + (size_t)(row - B_ROWS) * DIM);
    const float4 v = ((const float4*)src)[lane];
    float ss = v.x * v.x + v.y * v.y + v.z * v.z + v.w * v.w;
#pragma unroll
    for (int off = 1; off < 64; off <<= 1) ss += __shfl_xor(ss, off);
    const float rn = PRESCALE / fmaxf(sqrtf(ss), 1e-12f);
    bf16x4 h;
    h[0] = (__bf16)(v.x * rn); h[1] = (__bf16)(v.y * rn);
    h[2] = (__bf16)(v.z * rn); h[3] = (__bf16)(v.w * rn);
    const int p = row >> 4, r = row & 15;
    *(bf16x4*)(ebf + (size_t)p * 4096 + (lane >> 3) * 512 + ((lane >> 1) & 3) * 128
               + r * 8 + (lane & 1) * 4) = h;
    return;
  }

  const int c = blockIdx.x;
  unsigned long long bits = 0ull;
  int mycnt = 0;
#pragma unroll
  for (int it = 0; it < N_ROWS / 1024; ++it) {
    const int k = tid + it * 1024;
    const int lr = (k < B_ROWS) ? k : k - B_ROWS;
    if ((int)lab64[lr] == c) { bits |= (1ull << it); ++mycnt; }
  }
  int pre = mycnt;
#pragma unroll
  for (int off = 1; off < 64; off <<= 1) {
    const int o = __shfl_up(pre, off);
    if (lane >= off) pre += o;
  }
  if (lane == 63) woff[wv] = pre;
  __syncthreads();
  int wbase = 0, n = 0;
#pragma unroll
  for (int i = 0; i < 16; ++i) {
    const int wi = woff[i];
    wbase += (i < wv) ? wi : 0;
    n += wi;
  }
  if (n > WLCAP) n = WLCAP;
  int o = wbase + pre - mycnt;
#pragma unroll
  for (int it = 0; it < N_ROWS / 1024; ++it) {
    if ((bits >> it) & 1ull) {
      if (o < WLCAP) wl[o] = (unsigned short)(tid + it * 1024);
      ++o;
    }
  }
  __syncthreads();

  float4 a = {0.f, 0.f, 0.f, 0.f};
  for (int u = wv; u < n; u += 16) {
    const int row = wl[u];
    const float* src = (row < B_ROWS) ? (o1 + (size_t)row * DIM)
                                      : (o2 + (size_t)(row - B_ROWS) * DIM);
    const float4 v = ((const float4*)src)[lane];
    float ss = v.x * v.x + v.y * v.y + v.z * v.z + v.w * v.w;
#pragma unroll
    for (int off = 1; off < 64; off <<= 1) ss += __shfl_xor(ss, off);
    const float r = 1.0f / fmaxf(sqrtf(ss), 1e-12f);
    a.x += v.x * r; a.y += v.y * r; a.z += v.z * r; a.w += v.w * r;
  }
  *(float4*)&spart[wv][lane * 4] = a;
  __syncthreads();

  float s = 0.f;
  if (tid < DIM) {
#pragma unroll
    for (int i = 0; i < 16; ++i) s += spart[i][tid];
  }
  const float r2 = block_sum_1024(s * s, sbuf16);
  if (tid == 0) psum[c] = (n > 0) ? r2 / (float)n : 0.f;
}

// Kernel B: streaming Sexp per i-row via MFMA bf16. Byte-identical to the
// proven R10/R11 kernel (68 us): MREP=3, 3-buffer counted-vmcnt + setprio,
// SCALE pre-folded into ebf.
__global__ __launch_bounds__(256, 3) void lse_kernel(const __bf16* __restrict__ ebf,
                                                     float* __restrict__ ps) {
  __shared__ __align__(16) char smem[3 * 16384];
  const int bid = blockIdx.x;
  const int itile = bid / NCHUNK;
  const int chunk = bid - itile * NCHUNK;
  const int i0 = itile * ITILE;
  const int jbase = chunk * JCHUNK;
  const int tid = threadIdx.x;
  const int lane = tid & 63;
  const int w = tid >> 6;
  const char* const base = (const char*)ebf;

  bf16x8 a[MREP][8];
  {
    const char* ap = base + (size_t)((i0 >> 4) + w * MREP) * 8192 + lane * 16;
#pragma unroll
    for (int m = 0; m < MREP; ++m)
#pragma unroll
      for (int kc = 0; kc < 8; ++kc)
        a[m][kc] = *(const bf16x8*)(ap + m * 8192 + kc * 1024);
  }

  float s[MREP][4];
#pragma unroll
  for (int m = 0; m < MREP; ++m)
#pragma unroll
    for (int r = 0; r < 4; ++r) s[m][r] = 0.0f;

  const char* gsrc0 = base + (size_t)(jbase >> 4) * 8192 + w * 1024 + lane * 16;

#pragma unroll
  for (int q = 0; q < 4; ++q)
    gload_lds16(gsrc0 + q * 4096, smem + w * 1024 + q * 4096);
#pragma unroll
  for (int q = 0; q < 4; ++q)
    gload_lds16(gsrc0 + 16384 + q * 4096, smem + 16384 + w * 1024 + q * 4096);
  __syncthreads();

  int bsel = 0;
  for (int t = 0; t < NITER; ++t) {
    if (t + 2 < NITER) {
      const char* gs = gsrc0 + (size_t)(t + 2) * 16384;
      char* ldst = smem + ((bsel + 2) % 3) * 16384 + w * 1024;
#pragma unroll
      for (int q = 0; q < 4; ++q) gload_lds16(gs + q * 4096, ldst + q * 4096);
    }

    const char* lb = smem + bsel * 16384 + lane * 16;
    f32x4 acc[MREP][2];
#pragma unroll
    for (int m = 0; m < MREP; ++m) {
      acc[m][0] = (f32x4){0.0f, 0.0f, 0.0f, 0.0f};
      acc[m][1] = (f32x4){0.0f, 0.0f, 0.0f, 0.0f};
    }
    __builtin_amdgcn_s_setprio(1);
#pragma unroll
    for (int kc = 0; kc < 8; ++kc) {
      const bf16x8 b0 = *(const bf16x8*)(lb + kc * 1024);
      const bf16x8 b1 = *(const bf16x8*)(lb + kc * 1024 + 8192);
#pragma unroll
      for (int m = 0; m < MREP; ++m) {
        acc[m][0] = __builtin_amdgcn_mfma_f32_16x16x32_bf16(a[m][kc], b0, acc[m][0], 0, 0, 0);
        acc[m][1] = __builtin_amdgcn_mfma_f32_16x16x32_bf16(a[m][kc], b1, acc[m][1], 0, 0, 0);
      }
    }
    __builtin_amdgcn_s_setprio(0);
#pragma unroll
    for (int m = 0; m < MREP; ++m)
#pragma unroll
      for (int r = 0; r < 4; ++r)
        s[m][r] += __builtin_amdgcn_exp2f(acc[m][0][r])
                 + __builtin_amdgcn_exp2f(acc[m][1][r]);

    __builtin_amdgcn_sched_barrier(0);
    asm volatile("s_waitcnt lgkmcnt(0)" ::: "memory");
    if (t + 2 < NITER) {
      asm volatile("s_waitcnt vmcnt(4)" ::: "memory");
    } else {
      asm volatile("s_waitcnt vmcnt(0)" ::: "memory");
    }
    __builtin_amdgcn_sched_barrier(0);
    __builtin_amdgcn_s_barrier();
    __builtin_amdgcn_sched_barrier(0);

    bsel = (bsel + 1) % 3;
  }

#pragma unroll
  for (int off = 1; off < 16; off <<= 1)
#pragma unroll
    for (int m = 0; m < MREP; ++m)
#pragma unroll
      for (int r = 0; r < 4; ++r)
        s[m][r] += __shfl_xor(s[m][r], off);

  if ((lane & 15) == 0) {
    const int g = lane >> 4;
#pragma unroll
    for (int m = 0; m < MREP; ++m)
#pragma unroll
      for (int r = 0; r < 4; ++r) {
        const int i = i0 + w * 48 + m * 16 + g * 4 + r;
        ps[(size_t)i * NCHUNK + chunk] = s[m][r];
      }
  }
}

// Kernel C (fused finish+mean): 48 blocks; cnt zeroed by captured memset
// each launch -> the 48th atomicAdd arrival is genuinely the last block.
__global__ __launch_bounds__(256) void finishmean_kernel(
    const float* __restrict__ ps, const float* __restrict__ psum,
    float* __restrict__ partial, unsigned int* __restrict__ cnt,
    float* __restrict__ out) {
  __shared__ float sbuf[4];
  __shared__ int is_last;
  const int tid = threadIdx.x;
  const int row = blockIdx.x * 256 + tid;
  const float4 s0 = ((const float4*)(ps + (size_t)row * NCHUNK))[0];
  const float4 s1 = ((const float4*)(ps + (size_t)row * NCHUNK))[1];
  const float4 s2 = ((const float4*)(ps + (size_t)row * NCHUNK))[2];
  const float sm = (s0.x + s0.y + s0.z + s0.w) + (s1.x + s1.y + s1.z + s1.w)
                 + (s2.x + s2.y + s2.z + s2.w);
  const float p = block_sum_256(logf(sm), sbuf);
  if (tid == 0) {
    partial[blockIdx.x] = p;
    __threadfence();
    const unsigned int old = atomicAdd(cnt, 1u);
    is_last = (old == (unsigned)(FINBLK - 1)) ? 1 : 0;
  }
  __syncthreads();
  if (!is_last) return;
  __threadfence();
  float v = (tid < FINBLK) ? atomicAdd(&partial[tid], 0.0f) : 0.0f;
  const float vs = block_sum_256(v, sbuf);
  const float qs = block_sum_256(psum[tid] + psum[tid + 256], sbuf);
  if (tid == 0)
    out[0] = vs * (1.0f / (float)N_ROWS) - qs * (10.0f / (float)N_ROWS);
}

extern "C" void kernel_launch(void* const* d_in, const int* in_sizes, int n_in,
                              void* d_out, int out_size, void* d_ws, size_t ws_size,
                              hipStream_t stream) {
  const float* o1 = (const float*)d_in[0];
  const float* o2 = (const float*)d_in[1];
  const long long* labels = (const long long*)d_in[2];
  char* ws = (char*)d_ws;
  __bf16* ebf = (__bf16*)(ws + WS_EBF);
  float* ps = (float*)(ws + WS_PS);
  float* psum = (float*)(ws + WS_PSUM);
  float* partial = (float*)(ws + WS_PART);
  unsigned int* cnt = (unsigned int*)(ws + WS_CNT);

  hipMemsetAsync(cnt, 0, sizeof(unsigned int), stream);
  prep_classum_kernel<<<NCBLK + PREPBLK, 1024, 0, stream>>>(o1, o2, labels, ebf, psum);
  lse_kernel<<<NITILE * NCHUNK, 256, 0, stream>>>(ebf, ps);
  finishmean_kernel<<<FINBLK, 256, 0, stream>>>(ps, psum, partial, cnt, (float*)d_out);
}

// Round 19
// 90.705 us; speedup vs baseline: 1.3979x; 1.0054x over previous
//
#include <hip/hip_runtime.h>
#include <hip/hip_bf16.h>
#include <stdint.h>

#define B_ROWS 6144
#define N_ROWS 12288
#define DIM 256
#define NCLASS 512
#define NCHUNK 12
#define JCHUNK (N_ROWS / NCHUNK)   // 1024
#define NITER (JCHUNK / 32)        // 32
#define MREP 3
#define ITILE 192                  // 4 waves * 48 rows
#define NITILE (N_ROWS / ITILE)    // 64 -> 768 lse blocks
#define SCALE 14.426950408889634f  // log2(e)/0.1
#define PRESCALE 3.798282432f      // sqrt(SCALE); folded into embeddings
#define NCBLK NCLASS               // 512 classum blocks (merged, first)
#define WLCAP 128
#define PREPBLK (N_ROWS / 16)      // 768 prep blocks @1024 thr
#define FINBLK (N_ROWS / 256)      // 48

typedef float f32x4 __attribute__((ext_vector_type(4)));
typedef __bf16 bf16x8 __attribute__((ext_vector_type(8)));
typedef __bf16 bf16x4 __attribute__((ext_vector_type(4)));

// ---- workspace layout (bytes) ----
// ebf: swizzled bf16 of sqrt(SCALE)*normalized rows. Panel p = row>>4 (8 KB):
//   elem(row,d) = p*4096 + (d>>5)*512 + ((d>>3)&3)*128 + (row&15)*8 + (d&7)
#define WS_EBF  ((size_t)0)
#define WS_PS   ((size_t)(N_ROWS * DIM * 2))              // 6,291,456
#define WS_PSUM (WS_PS + (size_t)N_ROWS * NCHUNK * 4)     // + 589,824
#define WS_PART (WS_PSUM + (size_t)NCLASS * 4)            // + 2,048
#define WS_CNT  (WS_PART + (size_t)FINBLK * 4)            // + 192

__device__ inline void gload_lds16(const void* g, void* l) {
  __builtin_amdgcn_global_load_lds(
      (const __attribute__((address_space(1))) unsigned int*)g,
      (__attribute__((address_space(3))) unsigned int*)l, 16, 0, 0);
}

__device__ inline float block_sum_256(float v, float* sbuf) {
#pragma unroll
  for (int off = 32; off; off >>= 1) v += __shfl_down(v, off);
  const int lane = threadIdx.x & 63;
  const int w = threadIdx.x >> 6;
  __syncthreads();
  if (lane == 0) sbuf[w] = v;
  __syncthreads();
  return sbuf[0] + sbuf[1] + sbuf[2] + sbuf[3];
}

// Kernel A: prep only (wave per row, 16 rows/block @1024 thr). Proven.
__global__ __launch_bounds__(1024) void prep_kernel(
    const float* __restrict__ o1, const float* __restrict__ o2,
    __bf16* __restrict__ ebf) {
  const int tid = threadIdx.x;
  const int lane = tid & 63;
  const int row = blockIdx.x * 16 + (tid >> 6);
  const float* src = (row < B_ROWS) ? (o1 + (size_t)row * DIM)
                                    : (o2 + (size_t)(row - B_ROWS) * DIM);
  const float4 v = ((const float4*)src)[lane];
  float ss = v.x * v.x + v.y * v.y + v.z * v.z + v.w * v.w;
#pragma unroll
  for (int off = 1; off < 64; off <<= 1) ss += __shfl_xor(ss, off);
  const float rn = PRESCALE / fmaxf(sqrtf(ss), 1e-12f);
  bf16x4 h;
  h[0] = (__bf16)(v.x * rn); h[1] = (__bf16)(v.y * rn);
  h[2] = (__bf16)(v.z * rn); h[3] = (__bf16)(v.w * rn);
  const int p = row >> 4, r = row & 15;
  *(bf16x4*)(ebf + (size_t)p * 4096 + (lane >> 3) * 512 + ((lane >> 1) & 3) * 128
             + r * 8 + (lane & 1) * 4) = h;
}

// Kernel B (merged): blocks [0, NCBLK) = classum (R10-proven 256-thr path,
// latency-bound -> fills bubbles while co-resident with lse); blocks
// [NCBLK, NCBLK+768) = lse (R18 body, s_setprio REMOVED: m190 shows setprio
// hurts pre-8-phase GEMM-like kernels by starving co-wave ds_reads).
__global__ __launch_bounds__(256, 3) void classum_lse_kernel(
    const float* __restrict__ o1, const float* __restrict__ o2,
    const long long* __restrict__ lab64, const __bf16* __restrict__ ebf,
    float* __restrict__ psum, float* __restrict__ ps) {
  __shared__ __align__(16) char smem[3 * 16384];
  const int tid = threadIdx.x;
  const int lane = tid & 63;
  const int w = tid >> 6;

  if (blockIdx.x < NCBLK) {
    // ---- classum: block owns class c; psum[c] = ||S_c||^2 / n ----
    unsigned short* wl = (unsigned short*)smem;           // 256 B
    int* woff = (int*)(smem + 256);                       // 16 B
    float* sbuf = (float*)(smem + 288);                   // 16 B
    float* spart = (float*)(smem + 1024);                 // [4][256] = 4 KB
    const int c = blockIdx.x;

    unsigned long long bits = 0ull;
    int mycnt = 0;
#pragma unroll
    for (int it = 0; it < N_ROWS / 256; ++it) {
      const int k = tid + it * 256;
      const int lr = (k < B_ROWS) ? k : k - B_ROWS;
      if ((int)lab64[lr] == c) { bits |= (1ull << it); ++mycnt; }
    }
    int pre = mycnt;
#pragma unroll
    for (int off = 1; off < 64; off <<= 1) {
      const int o = __shfl_up(pre, off);
      if (lane >= off) pre += o;
    }
    if (lane == 63) woff[w] = pre;
    __syncthreads();
    int wbase = 0;
#pragma unroll
    for (int i = 0; i < 4; ++i) wbase += (i < w) ? woff[i] : 0;
    int n = woff[0] + woff[1] + woff[2] + woff[3];
    if (n > WLCAP) n = WLCAP;
    int o = wbase + pre - mycnt;
#pragma unroll
    for (int it = 0; it < N_ROWS / 256; ++it) {
      if ((bits >> it) & 1ull) {
        if (o < WLCAP) wl[o] = (unsigned short)(tid + it * 256);
        ++o;
      }
    }
    __syncthreads();

    float4 a = {0.f, 0.f, 0.f, 0.f};
    for (int u = w; u < n; u += 4) {
      const int row = wl[u];
      const float* src = (row < B_ROWS) ? (o1 + (size_t)row * DIM)
                                        : (o2 + (size_t)(row - B_ROWS) * DIM);
      const float4 v = ((const float4*)src)[lane];
      float ss = v.x * v.x + v.y * v.y + v.z * v.z + v.w * v.w;
#pragma unroll
      for (int off = 1; off < 64; off <<= 1) ss += __shfl_xor(ss, off);
      const float r = 1.0f / fmaxf(sqrtf(ss), 1e-12f);
      a.x += v.x * r; a.y += v.y * r; a.z += v.z * r; a.w += v.w * r;
    }
    *(float4*)(spart + w * DIM + lane * 4) = a;
    __syncthreads();

    const float s = spart[0 * DIM + tid] + spart[1 * DIM + tid]
                  + spart[2 * DIM + tid] + spart[3 * DIM + tid];
    const float r2 = block_sum_256(s * s, sbuf);
    if (tid == 0) psum[c] = (n > 0) ? r2 / (float)n : 0.f;
    return;
  }

  // ---- lse: streaming Sexp per i-row via MFMA bf16 (R18 minus setprio) ----
  const int lbid = blockIdx.x - NCBLK;
  const int itile = lbid / NCHUNK;
  const int chunk = lbid - itile * NCHUNK;
  const int i0 = itile * ITILE;
  const int jbase = chunk * JCHUNK;
  const char* const base = (const char*)ebf;

  bf16x8 a[MREP][8];
  {
    const char* ap = base + (size_t)((i0 >> 4) + w * MREP) * 8192 + lane * 16;
#pragma unroll
    for (int m = 0; m < MREP; ++m)
#pragma unroll
      for (int kc = 0; kc < 8; ++kc)
        a[m][kc] = *(const bf16x8*)(ap + m * 8192 + kc * 1024);
  }

  float s[MREP][4];
#pragma unroll
  for (int m = 0; m < MREP; ++m)
#pragma unroll
    for (int r = 0; r < 4; ++r) s[m][r] = 0.0f;

  const char* gsrc0 = base + (size_t)(jbase >> 4) * 8192 + w * 1024 + lane * 16;

#pragma unroll
  for (int q = 0; q < 4; ++q)
    gload_lds16(gsrc0 + q * 4096, smem + w * 1024 + q * 4096);
#pragma unroll
  for (int q = 0; q < 4; ++q)
    gload_lds16(gsrc0 + 16384 + q * 4096, smem + 16384 + w * 1024 + q * 4096);
  __syncthreads();

  int bsel = 0;
  for (int t = 0; t < NITER; ++t) {
    if (t + 2 < NITER) {
      const char* gs = gsrc0 + (size_t)(t + 2) * 16384;
      char* ldst = smem + ((bsel + 2) % 3) * 16384 + w * 1024;
#pragma unroll
      for (int q = 0; q < 4; ++q) gload_lds16(gs + q * 4096, ldst + q * 4096);
    }

    const char* lb = smem + bsel * 16384 + lane * 16;
    f32x4 acc[MREP][2];
#pragma unroll
    for (int m = 0; m < MREP; ++m) {
      acc[m][0] = (f32x4){0.0f, 0.0f, 0.0f, 0.0f};
      acc[m][1] = (f32x4){0.0f, 0.0f, 0.0f, 0.0f};
    }
#pragma unroll
    for (int kc = 0; kc < 8; ++kc) {
      const bf16x8 b0 = *(const bf16x8*)(lb + kc * 1024);
      const bf16x8 b1 = *(const bf16x8*)(lb + kc * 1024 + 8192);
#pragma unroll
      for (int m = 0; m < MREP; ++m) {
        acc[m][0] = __builtin_amdgcn_mfma_f32_16x16x32_bf16(a[m][kc], b0, acc[m][0], 0, 0, 0);
        acc[m][1] = __builtin_amdgcn_mfma_f32_16x16x32_bf16(a[m][kc], b1, acc[m][1], 0, 0, 0);
      }
    }
#pragma unroll
    for (int m = 0; m < MREP; ++m)
#pragma unroll
      for (int r = 0; r < 4; ++r)
        s[m][r] += __builtin_amdgcn_exp2f(acc[m][0][r])
                 + __builtin_amdgcn_exp2f(acc[m][1][r]);

    __builtin_amdgcn_sched_barrier(0);
    asm volatile("s_waitcnt lgkmcnt(0)" ::: "memory");
    if (t + 2 < NITER) {
      asm volatile("s_waitcnt vmcnt(4)" ::: "memory");
    } else {
      asm volatile("s_waitcnt vmcnt(0)" ::: "memory");
    }
    __builtin_amdgcn_sched_barrier(0);
    __builtin_amdgcn_s_barrier();
    __builtin_amdgcn_sched_barrier(0);

    bsel = (bsel + 1) % 3;
  }

#pragma unroll
  for (int off = 1; off < 16; off <<= 1)
#pragma unroll
    for (int m = 0; m < MREP; ++m)
#pragma unroll
      for (int r = 0; r < 4; ++r)
        s[m][r] += __shfl_xor(s[m][r], off);

  if ((lane & 15) == 0) {
    const int g = lane >> 4;
#pragma unroll
    for (int m = 0; m < MREP; ++m)
#pragma unroll
      for (int r = 0; r < 4; ++r) {
        const int i = i0 + w * 48 + m * 16 + g * 4 + r;
        ps[(size_t)i * NCHUNK + chunk] = s[m][r];
      }
  }
}

// Kernel C (fused finish+mean): 48 blocks; cnt zeroed by captured memset.
__global__ __launch_bounds__(256) void finishmean_kernel(
    const float* __restrict__ ps, const float* __restrict__ psum,
    float* __restrict__ partial, unsigned int* __restrict__ cnt,
    float* __restrict__ out) {
  __shared__ float sbuf[4];
  __shared__ int is_last;
  const int tid = threadIdx.x;
  const int row = blockIdx.x * 256 + tid;
  const float4 s0 = ((const float4*)(ps + (size_t)row * NCHUNK))[0];
  const float4 s1 = ((const float4*)(ps + (size_t)row * NCHUNK))[1];
  const float4 s2 = ((const float4*)(ps + (size_t)row * NCHUNK))[2];
  const float sm = (s0.x + s0.y + s0.z + s0.w) + (s1.x + s1.y + s1.z + s1.w)
                 + (s2.x + s2.y + s2.z + s2.w);
  const float p = block_sum_256(logf(sm), sbuf);
  if (tid == 0) {
    partial[blockIdx.x] = p;
    __threadfence();
    const unsigned int old = atomicAdd(cnt, 1u);
    is_last = (old == (unsigned)(FINBLK - 1)) ? 1 : 0;
  }
  __syncthreads();
  if (!is_last) return;
  __threadfence();
  float v = (tid < FINBLK) ? atomicAdd(&partial[tid], 0.0f) : 0.0f;
  const float vs = block_sum_256(v, sbuf);
  const float qs = block_sum_256(psum[tid] + psum[tid + 256], sbuf);
  if (tid == 0)
    out[0] = vs * (1.0f / (float)N_ROWS) - qs * (10.0f / (float)N_ROWS);
}

extern "C" void kernel_launch(void* const* d_in, const int* in_sizes, int n_in,
                              void* d_out, int out_size, void* d_ws, size_t ws_size,
                              hipStream_t stream) {
  const float* o1 = (const float*)d_in[0];
  const float* o2 = (const float*)d_in[1];
  const long long* labels = (const long long*)d_in[2];
  char* ws = (char*)d_ws;
  __bf16* ebf = (__bf16*)(ws + WS_EBF);
  float* ps = (float*)(ws + WS_PS);
  float* psum = (float*)(ws + WS_PSUM);
  float* partial = (float*)(ws + WS_PART);
  unsigned int* cnt = (unsigned int*)(ws + WS_CNT);

  hipMemsetAsync(cnt, 0, sizeof(unsigned int), stream);
  prep_kernel<<<PREPBLK, 1024, 0, stream>>>(o1, o2, ebf);
  classum_lse_kernel<<<NCBLK + NITILE * NCHUNK, 256, 0, stream>>>(
      o1, o2, labels, ebf, psum, ps);
  finishmean_kernel<<<FINBLK, 256, 0, stream>>>(ps, psum, partial, cnt, (float*)d_out);
}